// Round 1
// baseline (230.989 us; speedup 1.0000x reference)
//
#include <hip/hip_runtime.h>
#include <hip/hip_bf16.h>

// Problem constants (fixed by setup_inputs)
#define N_NODES 8192
#define N_FEAT  256
#define N_EDGES 131072
#define KPOW    4
#define OUT_LD  (KPOW * N_FEAT)   // 1024 floats per output row
#define HSIZE   262144            // 2^18 hash slots (load factor <= 0.5)
#define HMASK   (HSIZE - 1)

__device__ __forceinline__ unsigned hash_key(int key) {
    // Knuth multiplicative hash, take top 18 bits
    return ((unsigned)key * 2654435761u) >> 14;
}

// ---- Phase 1: duplicate detection hash ------------------------------------
// hkeys[slot] = (src*8192+dst) key; hmax[slot] = max edge index for that key.
__global__ void k_hash_insert(const int* __restrict__ ei,
                              int* __restrict__ hkeys, int* __restrict__ hmax) {
    int e = blockIdx.x * blockDim.x + threadIdx.x;
    if (e >= N_EDGES) return;
    int src = ei[e];
    int dst = ei[N_EDGES + e];
    int key = src * N_NODES + dst;
    unsigned slot = hash_key(key) & HMASK;
    for (;;) {
        int old = atomicCAS(&hkeys[slot], -1, key);
        if (old == -1 || old == key) {
            atomicMax(&hmax[slot], e);
            break;
        }
        slot = (slot + 1) & HMASK;
    }
}

__device__ __forceinline__ int find_slot(const int* __restrict__ hkeys, int key) {
    unsigned slot = hash_key(key) & HMASK;
    while (hkeys[slot] != key) slot = (slot + 1) & HMASK;
    return (int)slot;
}

// ---- Phase 2: per-row nnz histogram ---------------------------------------
// Directed entries: (row=dst, col=src, w) for ALL edges (the "+=" direction,
// duplicates accumulate), plus (row=src, col=dst, w) only for the LAST
// occurrence of each (src,dst) pair (the "=" direction, last-write-wins).
__global__ void k_count(const int* __restrict__ ei,
                        const int* __restrict__ hkeys, const int* __restrict__ hmax,
                        int* __restrict__ count) {
    int e = blockIdx.x * blockDim.x + threadIdx.x;
    if (e >= N_EDGES) return;
    int src = ei[e];
    int dst = ei[N_EDGES + e];
    atomicAdd(&count[dst], 1);
    int slot = find_slot(hkeys, src * N_NODES + dst);
    if (hmax[slot] == e) atomicAdd(&count[src], 1);
}

// ---- Phase 3: exclusive scan over 8192 counts (single block) --------------
__global__ void k_scan(const int* __restrict__ count,
                       int* __restrict__ rs, int* __restrict__ cursor) {
    __shared__ int sh[1024];
    int tid = threadIdx.x;
    int c[8];
    int tot = 0;
#pragma unroll
    for (int j = 0; j < 8; ++j) { c[j] = count[tid * 8 + j]; tot += c[j]; }
    sh[tid] = tot;
    __syncthreads();
    for (int off = 1; off < 1024; off <<= 1) {
        int v = (tid >= off) ? sh[tid - off] : 0;
        __syncthreads();
        sh[tid] += v;
        __syncthreads();
    }
    int base = sh[tid] - tot;  // exclusive prefix
#pragma unroll
    for (int j = 0; j < 8; ++j) {
        rs[tid * 8 + j] = base;
        cursor[tid * 8 + j] = base;
        base += c[j];
    }
    if (tid == 1023) rs[N_NODES] = base;
}

// ---- Phase 4: scatter edges into CSR --------------------------------------
__global__ void k_scatter(const int* __restrict__ ei, const float* __restrict__ ew,
                          const int* __restrict__ hkeys, const int* __restrict__ hmax,
                          int* __restrict__ cursor,
                          int* __restrict__ cols, float* __restrict__ wv) {
    int e = blockIdx.x * blockDim.x + threadIdx.x;
    if (e >= N_EDGES) return;
    int src = ei[e];
    int dst = ei[N_EDGES + e];
    float w = ew[e];
    int p = atomicAdd(&cursor[dst], 1);
    cols[p] = src;
    wv[p] = w;
    int slot = find_slot(hkeys, src * N_NODES + dst);
    if (hmax[slot] == e) {
        int p2 = atomicAdd(&cursor[src], 1);
        cols[p2] = dst;
        wv[p2] = w;
    }
}

// ---- Phase 5: copy x into out[:, 0:256] -----------------------------------
__global__ void k_copyx(const float* __restrict__ x, float* __restrict__ out) {
    int t = blockIdx.x * blockDim.x + threadIdx.x;  // one float4 per thread
    int row = t >> 6;
    int lane = t & 63;
    *(float4*)(out + (size_t)row * OUT_LD + lane * 4) =
        *(const float4*)(x + (size_t)row * N_FEAT + lane * 4);
}

// ---- Phase 6: CSR SpMM gather ---------------------------------------------
// hout[row, f] = sum_i wv[i] * hin[cols[i], f].  hin/hout point into d_out at
// column-block offsets; row stride is OUT_LD floats.  One wave per row, each
// lane owns 4 consecutive features (float4).  No atomics.
__global__ __launch_bounds__(256) void k_spmm(const int* __restrict__ rs,
                                              const int* __restrict__ cols,
                                              const float* __restrict__ wv,
                                              const float* __restrict__ hin,
                                              float* __restrict__ hout) {
    int wave = threadIdx.x >> 6;
    int lane = threadIdx.x & 63;
    int row = blockIdx.x * 4 + wave;
    int beg = rs[row];
    int end = rs[row + 1];
    float4 acc = make_float4(0.f, 0.f, 0.f, 0.f);
    for (int i = beg; i < end; ++i) {
        int c = cols[i];
        float w = wv[i];
        float4 hv = *(const float4*)(hin + (size_t)c * OUT_LD + lane * 4);
        acc.x += w * hv.x;
        acc.y += w * hv.y;
        acc.z += w * hv.z;
        acc.w += w * hv.w;
    }
    *(float4*)(hout + (size_t)row * OUT_LD + lane * 4) = acc;
}

extern "C" void kernel_launch(void* const* d_in, const int* in_sizes, int n_in,
                              void* d_out, int out_size, void* d_ws, size_t ws_size,
                              hipStream_t stream) {
    // d_in[0] = k (scalar, always 4 here), d_in[1] = x, d_in[2] = edge_index,
    // d_in[3] = edge_weight
    const float* x  = (const float*)d_in[1];
    const int*   ei = (const int*)d_in[2];
    const float* ew = (const float*)d_in[3];
    float* out = (float*)d_out;

    // Workspace layout (ints unless noted):
    //   hkeys[HSIZE] | hmax[HSIZE] | count[8192] | rs[8200] | cursor[8192]
    //   | cols[2*N_EDGES] | wv[2*N_EDGES] (float)
    int* hkeys  = (int*)d_ws;
    int* hmax   = hkeys + HSIZE;
    int* count  = hmax + HSIZE;
    int* rs     = count + N_NODES;
    int* cursor = rs + (N_NODES + 8);       // rs needs N_NODES+1; padded to +8
    int* cols   = cursor + N_NODES;
    float* wv   = (float*)(cols + 2 * N_EDGES);

    // Init: hash keys & max to -1 (0xFF bytes), counts to 0.
    hipMemsetAsync(hkeys, 0xFF, (size_t)2 * HSIZE * sizeof(int), stream);
    hipMemsetAsync(count, 0, (size_t)N_NODES * sizeof(int), stream);

    const int TB = 256;
    const int EB = (N_EDGES + TB - 1) / TB;       // 512 blocks

    k_hash_insert<<<EB, TB, 0, stream>>>(ei, hkeys, hmax);
    k_count<<<EB, TB, 0, stream>>>(ei, hkeys, hmax, count);
    k_scan<<<1, 1024, 0, stream>>>(count, rs, cursor);
    k_scatter<<<EB, TB, 0, stream>>>(ei, ew, hkeys, hmax, cursor, cols, wv);

    // out[:, 0:256] = x
    k_copyx<<<(N_NODES * 64) / TB, TB, 0, stream>>>(x, out);

    // out[:, j*256:(j+1)*256] = A @ out[:, (j-1)*256:j*256]
    for (int j = 1; j < KPOW; ++j) {
        const float* hin = out + (size_t)(j - 1) * N_FEAT;
        float* hout      = out + (size_t)j * N_FEAT;
        k_spmm<<<N_NODES / 4, TB, 0, stream>>>(rs, cols, wv, hin, hout);
    }
}

// Round 2
// 200.013 us; speedup vs baseline: 1.1549x; 1.1549x over previous
//
#include <hip/hip_runtime.h>
#include <hip/hip_bf16.h>

// Problem constants (fixed by setup_inputs)
#define N_NODES 8192
#define N_FEAT  256
#define N_EDGES 131072
#define KPOW    4
#define OUT_LD  (KPOW * N_FEAT)   // 1024 floats per output row
#define HSIZE   262144            // 2^18 hash slots (load factor <= 0.5)
#define HMASK   (HSIZE - 1)

__device__ __forceinline__ unsigned hash_key(int key) {
    return ((unsigned)key * 2654435761u) >> 14;
}

__device__ __forceinline__ float bf2f(unsigned short u) {
    union { unsigned int i; float f; } v;
    v.i = (unsigned int)u << 16;
    return v.f;
}

__device__ __forceinline__ unsigned short f2bf(float f) {
    union { float f; unsigned int i; } v = { f };
    unsigned int x = v.i;
    // round-to-nearest-even (values are finite/normal here)
    return (unsigned short)((x + 0x7fffu + ((x >> 16) & 1u)) >> 16);
}

// ---- Phase 1: duplicate detection hash ------------------------------------
// hkeys[slot] = (src*8192+dst) key; hmax[slot] = max edge index for that key.
// Needed because the reference does adj[src,dst] = w (LAST write wins for
// duplicate pairs) then adj[dst,src] += w (duplicates ACCUMULATE).
__global__ void k_hash_insert(const int* __restrict__ ei,
                              int* __restrict__ hkeys, int* __restrict__ hmax) {
    int e = blockIdx.x * blockDim.x + threadIdx.x;
    if (e >= N_EDGES) return;
    int src = ei[e];
    int dst = ei[N_EDGES + e];
    int key = src * N_NODES + dst;
    unsigned slot = hash_key(key) & HMASK;
    for (;;) {
        int old = atomicCAS(&hkeys[slot], -1, key);
        if (old == -1 || old == key) {
            atomicMax(&hmax[slot], e);
            break;
        }
        slot = (slot + 1) & HMASK;
    }
}

__device__ __forceinline__ int find_slot(const int* __restrict__ hkeys, int key) {
    unsigned slot = hash_key(key) & HMASK;
    while (hkeys[slot] != key) slot = (slot + 1) & HMASK;
    return (int)slot;
}

// ---- Phase 2: per-row nnz histogram ---------------------------------------
__global__ void k_count(const int* __restrict__ ei,
                        const int* __restrict__ hkeys, const int* __restrict__ hmax,
                        int* __restrict__ count) {
    int e = blockIdx.x * blockDim.x + threadIdx.x;
    if (e >= N_EDGES) return;
    int src = ei[e];
    int dst = ei[N_EDGES + e];
    atomicAdd(&count[dst], 1);
    int slot = find_slot(hkeys, src * N_NODES + dst);
    if (hmax[slot] == e) atomicAdd(&count[src], 1);
}

// ---- Phase 3: exclusive scan over 8192 counts (single block) --------------
__global__ void k_scan(const int* __restrict__ count,
                       int* __restrict__ rs, int* __restrict__ cursor) {
    __shared__ int sh[1024];
    int tid = threadIdx.x;
    int c[8];
    int tot = 0;
#pragma unroll
    for (int j = 0; j < 8; ++j) { c[j] = count[tid * 8 + j]; tot += c[j]; }
    sh[tid] = tot;
    __syncthreads();
    for (int off = 1; off < 1024; off <<= 1) {
        int v = (tid >= off) ? sh[tid - off] : 0;
        __syncthreads();
        sh[tid] += v;
        __syncthreads();
    }
    int base = sh[tid] - tot;  // exclusive prefix
#pragma unroll
    for (int j = 0; j < 8; ++j) {
        rs[tid * 8 + j] = base;
        cursor[tid * 8 + j] = base;
        base += c[j];
    }
    if (tid == 1023) rs[N_NODES] = base;
}

// ---- Phase 4: scatter edges into CSR --------------------------------------
__global__ void k_scatter(const int* __restrict__ ei, const float* __restrict__ ew,
                          const int* __restrict__ hkeys, const int* __restrict__ hmax,
                          int* __restrict__ cursor,
                          int* __restrict__ cols, float* __restrict__ wv) {
    int e = blockIdx.x * blockDim.x + threadIdx.x;
    if (e >= N_EDGES) return;
    int src = ei[e];
    int dst = ei[N_EDGES + e];
    float w = ew[e];
    int p = atomicAdd(&cursor[dst], 1);
    cols[p] = src;
    wv[p] = w;
    int slot = find_slot(hkeys, src * N_NODES + dst);
    if (hmax[slot] == e) {
        int p2 = atomicAdd(&cursor[src], 1);
        cols[p2] = dst;
        wv[p2] = w;
    }
}

// ---- Phase 5: copy x into out[:, 0:256] (fp32) and xb (bf16) --------------
__global__ void k_copyx(const float* __restrict__ x, float* __restrict__ out,
                        unsigned short* __restrict__ xb) {
    int t = blockIdx.x * blockDim.x + threadIdx.x;  // one float4 per thread
    int row = t >> 6;
    int lane = t & 63;
    float4 v = *(const float4*)(x + (size_t)row * N_FEAT + lane * 4);
    *(float4*)(out + (size_t)row * OUT_LD + lane * 4) = v;
    ushort4 b;
    b.x = f2bf(v.x); b.y = f2bf(v.y); b.z = f2bf(v.z); b.w = f2bf(v.w);
    *(ushort4*)(xb + (size_t)row * N_FEAT + lane * 4) = b;
}

// ---- Phase 6: CSR SpMM gather (bf16 in, fp32 accumulate) ------------------
// hout[row, f] = sum_i wv[i] * hin_bf16[cols[i], f].  One wave per row, each
// lane owns 4 consecutive features (ushort4 = 8 B gather per lane -> 512 B
// per nonzero-row, half the fp32 traffic).  Writes fp32 into the out column
// block and (unless last hop) a bf16 staging copy for the next hop's gather.
__global__ __launch_bounds__(256) void k_spmm(const int* __restrict__ rs,
                                              const int* __restrict__ cols,
                                              const float* __restrict__ wv,
                                              const unsigned short* __restrict__ hinb,
                                              float* __restrict__ hout,
                                              unsigned short* __restrict__ houtb,
                                              int write_bf) {
    int wave = threadIdx.x >> 6;
    int lane = threadIdx.x & 63;
    int row = blockIdx.x * 4 + wave;
    int beg = rs[row];
    int end = rs[row + 1];
    float ax = 0.f, ay = 0.f, az = 0.f, aw = 0.f;
    int i = beg;
    for (; i + 1 < end; i += 2) {
        int c0 = cols[i], c1 = cols[i + 1];
        float w0 = wv[i], w1 = wv[i + 1];
        ushort4 u0 = *(const ushort4*)(hinb + (size_t)c0 * N_FEAT + lane * 4);
        ushort4 u1 = *(const ushort4*)(hinb + (size_t)c1 * N_FEAT + lane * 4);
        ax += w0 * bf2f(u0.x) + w1 * bf2f(u1.x);
        ay += w0 * bf2f(u0.y) + w1 * bf2f(u1.y);
        az += w0 * bf2f(u0.z) + w1 * bf2f(u1.z);
        aw += w0 * bf2f(u0.w) + w1 * bf2f(u1.w);
    }
    if (i < end) {
        int c0 = cols[i];
        float w0 = wv[i];
        ushort4 u0 = *(const ushort4*)(hinb + (size_t)c0 * N_FEAT + lane * 4);
        ax += w0 * bf2f(u0.x);
        ay += w0 * bf2f(u0.y);
        az += w0 * bf2f(u0.z);
        aw += w0 * bf2f(u0.w);
    }
    *(float4*)(hout + (size_t)row * OUT_LD + lane * 4) =
        make_float4(ax, ay, az, aw);
    if (write_bf) {
        ushort4 b;
        b.x = f2bf(ax); b.y = f2bf(ay); b.z = f2bf(az); b.w = f2bf(aw);
        *(ushort4*)(houtb + (size_t)row * N_FEAT + lane * 4) = b;
    }
}

extern "C" void kernel_launch(void* const* d_in, const int* in_sizes, int n_in,
                              void* d_out, int out_size, void* d_ws, size_t ws_size,
                              hipStream_t stream) {
    // d_in[0] = k (scalar, =4), d_in[1] = x, d_in[2] = edge_index, d_in[3] = edge_weight
    const float* x  = (const float*)d_in[1];
    const int*   ei = (const int*)d_in[2];
    const float* ew = (const float*)d_in[3];
    float* out = (float*)d_out;

    // Workspace layout:
    //   hkeys[HSIZE] hmax[HSIZE] count[8192] rs[8200] cursor[8192]
    //   cols[2*N_EDGES] wv[2*N_EDGES]  hb0|hb1|hb2 (bf16, 8192*256 each)
    int* hkeys  = (int*)d_ws;
    int* hmax   = hkeys + HSIZE;
    int* count  = hmax + HSIZE;
    int* rs     = count + N_NODES;
    int* cursor = rs + (N_NODES + 8);
    int* cols   = cursor + N_NODES;
    float* wv   = (float*)(cols + 2 * N_EDGES);
    unsigned short* hb0 = (unsigned short*)(wv + 2 * N_EDGES);
    unsigned short* hb1 = hb0 + (size_t)N_NODES * N_FEAT;
    unsigned short* hb2 = hb1 + (size_t)N_NODES * N_FEAT;

    hipMemsetAsync(hkeys, 0xFF, (size_t)2 * HSIZE * sizeof(int), stream);
    hipMemsetAsync(count, 0, (size_t)N_NODES * sizeof(int), stream);

    const int TB = 256;
    const int EB = (N_EDGES + TB - 1) / TB;       // 512 blocks

    k_hash_insert<<<EB, TB, 0, stream>>>(ei, hkeys, hmax);
    k_count<<<EB, TB, 0, stream>>>(ei, hkeys, hmax, count);
    k_scan<<<1, 1024, 0, stream>>>(count, rs, cursor);
    k_scatter<<<EB, TB, 0, stream>>>(ei, ew, hkeys, hmax, cursor, cols, wv);

    // out[:, 0:256] = x ; xb = bf16(x)
    k_copyx<<<(N_NODES * 64) / TB, TB, 0, stream>>>(x, out, hb0);

    // hop j: out[:, j*256:(j+1)*256] = A @ h_{j-1} (bf16-staged gather)
    const unsigned short* hin = hb0;
    for (int j = 1; j < KPOW; ++j) {
        float* hout = out + (size_t)j * N_FEAT;
        unsigned short* houtb = (j == 1) ? hb1 : hb2;
        int write_bf = (j < KPOW - 1) ? 1 : 0;
        k_spmm<<<N_NODES / 4, TB, 0, stream>>>(rs, cols, wv, hin, hout, houtb, write_bf);
        hin = houtb;
    }
}

// Round 3
// 150.471 us; speedup vs baseline: 1.5351x; 1.3292x over previous
//
#include <hip/hip_runtime.h>
#include <hip/hip_bf16.h>

// Problem constants (fixed by setup_inputs)
#define N_NODES 8192
#define N_FEAT  256
#define N_EDGES 131072
#define KPOW    4
#define OUT_LD  (KPOW * N_FEAT)   // 1024 floats per output row
#define COL_MASK 8191u            // low 13 bits = column
// Packed set-direction entry: (1<<30) | (edge_id<<13) | col.
// Add-direction entry: just col (high bits 0).  For equal col, packed-value
// order == edge-id order among set entries, and add entries never compare
// greater than any set entry.

__device__ __forceinline__ float bf2f(unsigned short u) {
    union { unsigned int i; float f; } v;
    v.i = (unsigned int)u << 16;
    return v.f;
}

__device__ __forceinline__ unsigned short f2bf(float f) {
    union { float f; unsigned int i; } v = { f };
    unsigned int x = v.i;
    return (unsigned short)((x + 0x7fffu + ((x >> 16) & 1u)) >> 16);
}

// ---- Phase 0: zero the per-row counters -----------------------------------
__global__ void k_init(int* __restrict__ count) {
    int t = blockIdx.x * blockDim.x + threadIdx.x;   // 8 blocks * 256 * int4
    *(int4*)(count + t * 4) = make_int4(0, 0, 0, 0);
}

// ---- Phase 1: per-row nnz histogram (both directions, every edge) ---------
__global__ void k_count(const int* __restrict__ ei, int* __restrict__ count) {
    int e = blockIdx.x * blockDim.x + threadIdx.x;
    if (e >= N_EDGES) return;
    int src = ei[e];
    int dst = ei[N_EDGES + e];
    atomicAdd(&count[dst], 1);   // add-direction row
    atomicAdd(&count[src], 1);   // set-direction row (dups resolved later)
}

// ---- Phase 2: exclusive scan over 8192 counts (single block) --------------
__global__ void k_scan(const int* __restrict__ count,
                       int* __restrict__ rs, int* __restrict__ cursor) {
    __shared__ int sh[1024];
    int tid = threadIdx.x;
    int c[8];
    int tot = 0;
#pragma unroll
    for (int j = 0; j < 8; ++j) { c[j] = count[tid * 8 + j]; tot += c[j]; }
    sh[tid] = tot;
    __syncthreads();
    for (int off = 1; off < 1024; off <<= 1) {
        int v = (tid >= off) ? sh[tid - off] : 0;
        __syncthreads();
        sh[tid] += v;
        __syncthreads();
    }
    int base = sh[tid] - tot;  // exclusive prefix
#pragma unroll
    for (int j = 0; j < 8; ++j) {
        rs[tid * 8 + j] = base;
        cursor[tid * 8 + j] = base;
        base += c[j];
    }
    if (tid == 1023) rs[N_NODES] = base;
}

// ---- Phase 3 (fused): copy x -> out block 0 + bf16 stage | scatter CSR ----
__global__ void k_scatter_copy(const int* __restrict__ ei, const float* __restrict__ ew,
                               int* __restrict__ cursor,
                               unsigned* __restrict__ cols, float* __restrict__ wv,
                               const float* __restrict__ x, float* __restrict__ out,
                               unsigned short* __restrict__ xb) {
    if (blockIdx.x < 2048) {
        // copyx: one float4 per thread
        int t = blockIdx.x * blockDim.x + threadIdx.x;
        int row = t >> 6;
        int lane = t & 63;
        float4 v = *(const float4*)(x + (size_t)row * N_FEAT + lane * 4);
        *(float4*)(out + (size_t)row * OUT_LD + lane * 4) = v;
        ushort4 b;
        b.x = f2bf(v.x); b.y = f2bf(v.y); b.z = f2bf(v.z); b.w = f2bf(v.w);
        *(ushort4*)(xb + (size_t)row * N_FEAT + lane * 4) = b;
    } else {
        int e = (blockIdx.x - 2048) * blockDim.x + threadIdx.x;
        if (e >= N_EDGES) return;
        int src = ei[e];
        int dst = ei[N_EDGES + e];
        float w = ew[e];
        int p = atomicAdd(&cursor[dst], 1);          // add-direction
        cols[p] = (unsigned)src;
        wv[p] = w;
        int q = atomicAdd(&cursor[src], 1);          // set-direction (tagged)
        cols[q] = (1u << 30) | ((unsigned)e << 13) | (unsigned)dst;
        wv[q] = w;
    }
}

// ---- Phase 4: CSR SpMM gather (bf16 in, fp32 accumulate) ------------------
// One wave per row.  Per 64-entry chunk: coalesced load of (col,w) into
// lanes, then broadcast via __shfl in groups of 8 -> 8 independent gathers in
// flight, no memory op on the address critical path.  DEDUP (spmm1 only):
// among set-tagged entries of this row with equal col, only the max edge-id
// survives (last-write-wins of the reference's adj.at[src,dst].set);
// killed weights are zeroed in-register and written back for hops 2-3.
__global__ __launch_bounds__(256) void k_spmm(const int* __restrict__ rs,
                                              const unsigned* __restrict__ cols,
                                              float* __restrict__ wv,
                                              const unsigned short* __restrict__ hinb,
                                              float* __restrict__ hout,
                                              unsigned short* __restrict__ houtb,
                                              int write_bf, int dedup) {
    int wave = threadIdx.x >> 6;
    int lane = threadIdx.x & 63;
    int row = blockIdx.x * 4 + wave;
    int beg = rs[row];
    int end = rs[row + 1];
    float ax = 0.f, ay = 0.f, az = 0.f, aw = 0.f;

    for (int base = beg; base < end; base += 64) {
        int p = base + lane;
        bool valid = p < end;
        unsigned v = valid ? cols[p] : 0u;
        float w = valid ? wv[p] : 0.f;

        if (dedup && (v >> 30)) {
            bool kill = false;
            if (end - beg <= 64) {
                int n = end - beg;
                for (int j = 0; j < n; ++j) {
                    unsigned vj = (unsigned)__shfl((int)v, j);
                    kill |= (((vj ^ v) & COL_MASK) == 0u) && (vj > v);
                }
            } else {
                for (int j = beg; j < end; ++j) {
                    unsigned vj = cols[j];
                    kill |= (((vj ^ v) & COL_MASK) == 0u) && (vj > v);
                }
            }
            if (kill) { w = 0.f; wv[p] = 0.f; }
        }

        unsigned c = v & COL_MASK;
        int n = end - base; if (n > 64) n = 64;   // entries in this chunk
        for (int j = 0; j < n; j += 8) {
            int cc[8]; float ww[8];
#pragma unroll
            for (int k = 0; k < 8; ++k) {
                cc[k] = __shfl((int)c, j + k);     // pads: c=0, w=0
                ww[k] = __shfl(w, j + k);
            }
            ushort4 u[8];
#pragma unroll
            for (int k = 0; k < 8; ++k)
                u[k] = *(const ushort4*)(hinb + (size_t)cc[k] * N_FEAT + lane * 4);
#pragma unroll
            for (int k = 0; k < 8; ++k) {
                ax += ww[k] * bf2f(u[k].x);
                ay += ww[k] * bf2f(u[k].y);
                az += ww[k] * bf2f(u[k].z);
                aw += ww[k] * bf2f(u[k].w);
            }
        }
    }

    *(float4*)(hout + (size_t)row * OUT_LD + lane * 4) =
        make_float4(ax, ay, az, aw);
    if (write_bf) {
        ushort4 b;
        b.x = f2bf(ax); b.y = f2bf(ay); b.z = f2bf(az); b.w = f2bf(aw);
        *(ushort4*)(houtb + (size_t)row * N_FEAT + lane * 4) = b;
    }
}

extern "C" void kernel_launch(void* const* d_in, const int* in_sizes, int n_in,
                              void* d_out, int out_size, void* d_ws, size_t ws_size,
                              hipStream_t stream) {
    // d_in[0]=k (scalar, =4), d_in[1]=x, d_in[2]=edge_index, d_in[3]=edge_weight
    const float* x  = (const float*)d_in[1];
    const int*   ei = (const int*)d_in[2];
    const float* ew = (const float*)d_in[3];
    float* out = (float*)d_out;

    // Workspace: count[8192] rs[8200] cursor[8192] cols[2E] wv[2E]
    //            hb0|hb1|hb2 (bf16, 8192*256 each)
    int* count  = (int*)d_ws;
    int* rs     = count + N_NODES;
    int* cursor = rs + (N_NODES + 8);
    unsigned* cols = (unsigned*)(cursor + N_NODES);
    float* wv   = (float*)(cols + 2 * N_EDGES);
    unsigned short* hb0 = (unsigned short*)(wv + 2 * N_EDGES);
    unsigned short* hb1 = hb0 + (size_t)N_NODES * N_FEAT;
    unsigned short* hb2 = hb1 + (size_t)N_NODES * N_FEAT;

    const int TB = 256;
    const int EB = N_EDGES / TB;              // 512

    k_init<<<N_NODES / (TB * 4), TB, 0, stream>>>(count);          // 8 blocks
    k_count<<<EB, TB, 0, stream>>>(ei, count);
    k_scan<<<1, 1024, 0, stream>>>(count, rs, cursor);
    k_scatter_copy<<<2048 + EB, TB, 0, stream>>>(ei, ew, cursor, cols, wv,
                                                 x, out, hb0);

    // hop j: out[:, j*256:(j+1)*256] = A @ h_{j-1}
    const unsigned short* hin = hb0;
    for (int j = 1; j < KPOW; ++j) {
        float* hout = out + (size_t)j * N_FEAT;
        unsigned short* houtb = (j == 1) ? hb1 : hb2;
        int write_bf = (j < KPOW - 1) ? 1 : 0;
        int dedup = (j == 1) ? 1 : 0;
        k_spmm<<<N_NODES / 4, TB, 0, stream>>>(rs, cols, wv, hin, hout, houtb,
                                               write_bf, dedup);
        hin = houtb;
    }
}

// Round 4
// 145.695 us; speedup vs baseline: 1.5854x; 1.0328x over previous
//
#include <hip/hip_runtime.h>

// Problem constants (fixed by setup_inputs)
#define N_NODES 8192
#define N_FEAT  256
#define N_EDGES 131072
#define KPOW    4
#define OUT_LD  1024          // k*F floats per output row
#define RCAP    128           // ELL slots per row (Poisson(64) max ~100; safe)
#define COL_MASK 8191u        // low 13 bits = column
// Entry col_word: add-direction = src (untagged).  Set-direction =
// (1<<30) | (edge_id<<13) | dst.  Among same-col tagged entries, packed
// order == edge-id order, so "last write wins" = keep max col_word.

static __device__ __forceinline__ float bflo(unsigned u) {
    union { unsigned i; float f; } v; v.i = u << 16; return v.f;
}
static __device__ __forceinline__ float bfhi(unsigned u) {
    union { unsigned i; float f; } v; v.i = u & 0xffff0000u; return v.f;
}
static __device__ __forceinline__ unsigned short f2bf(float f) {
    union { float f; unsigned i; } v = { f };
    return (unsigned short)((v.i + 0x7fffu + ((v.i >> 16) & 1u)) >> 16);
}

// ---- Phase 1 (fused): copy x -> out block0 + bf16 stage | ELL scatter -----
__global__ void k_scatter_copy(const int* __restrict__ ei, const float* __restrict__ ew,
                               int* __restrict__ len, uint2* __restrict__ ent,
                               const float* __restrict__ x, float* __restrict__ out,
                               unsigned short* __restrict__ xb) {
    if (blockIdx.x < 2048) {
        // copyx: one float4 per thread
        int t = blockIdx.x * blockDim.x + threadIdx.x;
        int row = t >> 6;
        int lane = t & 63;
        float4 v = *(const float4*)(x + (size_t)row * N_FEAT + lane * 4);
        *(float4*)(out + (size_t)row * OUT_LD + lane * 4) = v;
        ushort4 b;
        b.x = f2bf(v.x); b.y = f2bf(v.y); b.z = f2bf(v.z); b.w = f2bf(v.w);
        *(ushort4*)(xb + (size_t)row * N_FEAT + lane * 4) = b;
    } else {
        int e = (blockIdx.x - 2048) * blockDim.x + threadIdx.x;
        if (e >= N_EDGES) return;
        int src = ei[e];
        int dst = ei[N_EDGES + e];
        unsigned wbits = __float_as_uint(ew[e]);
        int s0 = atomicAdd(&len[dst], 1);                 // add-direction
        if (s0 < RCAP) ent[(size_t)dst * RCAP + s0] = make_uint2((unsigned)src, wbits);
        int s1 = atomicAdd(&len[src], 1);                 // set-direction (tagged)
        if (s1 < RCAP) ent[(size_t)src * RCAP + s1] =
            make_uint2((1u << 30) | ((unsigned)e << 13) | (unsigned)dst, wbits);
    }
}

// ---- Phase 2: per-row dedup of set-direction duplicates -------------------
// One wave per row.  A tagged entry is killed (w=0) iff another entry with
// the same col compares greater (greater => also tagged, higher edge id).
// Unwritten ELL slots are zeros (untagged, w=0): inert.
__global__ __launch_bounds__(256) void k_dedup(uint2* __restrict__ ent) {
    int lane = threadIdx.x & 63;
    int row = blockIdx.x * 4 + (threadIdx.x >> 6);
    size_t base = (size_t)row * RCAP;
    unsigned v0 = ent[base + lane].x;
    unsigned v1 = ent[base + 64 + lane].x;
    bool k0 = false, k1 = false;
    for (int j = 0; j < 64; ++j) {
        unsigned b = (unsigned)__shfl((int)v0, j);
        if (b >> 30) {     // wave-uniform branch: skip untagged broadcasters
            k0 |= (((b ^ v0) & COL_MASK) == 0u) && (b > v0);
            k1 |= (((b ^ v1) & COL_MASK) == 0u) && (b > v1);
        }
        unsigned b2 = (unsigned)__shfl((int)v1, j);
        if (b2 >> 30) {
            k0 |= (((b2 ^ v0) & COL_MASK) == 0u) && (b2 > v0);
            k1 |= (((b2 ^ v1) & COL_MASK) == 0u) && (b2 > v1);
        }
    }
    if (k0 && (v0 >> 30)) ent[base + lane].y = 0u;
    if (k1 && (v1 >> 30)) ent[base + 64 + lane].y = 0u;
}

// ---- Phase 3: ELL SpMM gather (bf16 in, fp32 accumulate) ------------------
// One wave per row.  Entries are wave-uniform -> scalar loads (s_load) via
// readfirstlane(row); gather addresses are SGPR base + lane*8: no VALU
// address math, no shuffles.  Next entry group is software-prefetched.
__global__ __launch_bounds__(256) void k_spmm(const int* __restrict__ len,
                                              const uint2* __restrict__ ent,
                                              const unsigned short* __restrict__ hinb,
                                              float* __restrict__ hout,
                                              unsigned short* __restrict__ houtb,
                                              int write_bf) {
    int lane = threadIdx.x & 63;
    int row = __builtin_amdgcn_readfirstlane(blockIdx.x * 4 + (threadIdx.x >> 6));
    int n = len[row];
    if (n > RCAP) n = RCAP;
    const uint4* e4 = (const uint4*)(ent + (size_t)row * RCAP);  // 2 entries per uint4
    float ax = 0.f, ay = 0.f, az = 0.f, aw = 0.f;
    int ng = (n + 7) >> 3;          // groups of 8 entries (zero-padded slots inert)

    uint4 q0, q1, q2, q3;
    if (ng > 0) { q0 = e4[0]; q1 = e4[1]; q2 = e4[2]; q3 = e4[3]; }
    for (int g = 0; g < ng; ++g) {
        int gp = (g + 1 < 16) ? (g + 1) : 0;   // clamped prefetch index
        uint4 p0 = e4[gp * 4 + 0], p1 = e4[gp * 4 + 1],
              p2 = e4[gp * 4 + 2], p3 = e4[gp * 4 + 3];
        uint4 qq[4] = { q0, q1, q2, q3 };
#pragma unroll
        for (int k = 0; k < 4; ++k) {
            unsigned ca = qq[k].x & COL_MASK; float wa = __uint_as_float(qq[k].y);
            unsigned cb = qq[k].z & COL_MASK; float wb = __uint_as_float(qq[k].w);
            uint2 ua = *(const uint2*)(hinb + (size_t)ca * N_FEAT + lane * 4);
            uint2 ub = *(const uint2*)(hinb + (size_t)cb * N_FEAT + lane * 4);
            ax += wa * bflo(ua.x); ay += wa * bfhi(ua.x);
            az += wa * bflo(ua.y); aw += wa * bfhi(ua.y);
            ax += wb * bflo(ub.x); ay += wb * bfhi(ub.x);
            az += wb * bflo(ub.y); aw += wb * bfhi(ub.y);
        }
        q0 = p0; q1 = p1; q2 = p2; q3 = p3;
    }

    *(float4*)(hout + (size_t)row * OUT_LD + lane * 4) =
        make_float4(ax, ay, az, aw);
    if (write_bf) {
        ushort4 b;
        b.x = f2bf(ax); b.y = f2bf(ay); b.z = f2bf(az); b.w = f2bf(aw);
        *(ushort4*)(houtb + (size_t)row * N_FEAT + lane * 4) = b;
    }
}

extern "C" void kernel_launch(void* const* d_in, const int* in_sizes, int n_in,
                              void* d_out, int out_size, void* d_ws, size_t ws_size,
                              hipStream_t stream) {
    // d_in[0]=k (=4, ignored), d_in[1]=x, d_in[2]=edge_index, d_in[3]=edge_weight
    const float* x  = (const float*)d_in[1];
    const int*   ei = (const int*)d_in[2];
    const float* ew = (const float*)d_in[3];
    float* out = (float*)d_out;

    // Workspace: len[8192] | ent[8192*128 uint2] | hb0|hb1|hb2 (bf16 4MB each)
    int* len   = (int*)d_ws;
    uint2* ent = (uint2*)(len + N_NODES);
    unsigned short* hb0 = (unsigned short*)(ent + (size_t)N_NODES * RCAP);
    unsigned short* hb1 = hb0 + (size_t)N_NODES * N_FEAT;
    unsigned short* hb2 = hb1 + (size_t)N_NODES * N_FEAT;

    // Zero len + ent in one memset (8.4 MB): unwritten ELL slots become inert.
    hipMemsetAsync(d_ws, 0, (size_t)N_NODES * sizeof(int)
                            + (size_t)N_NODES * RCAP * sizeof(uint2), stream);

    const int TB = 256;
    const int EB = N_EDGES / TB;                  // 512

    k_scatter_copy<<<2048 + EB, TB, 0, stream>>>(ei, ew, len, ent, x, out, hb0);
    k_dedup<<<N_NODES / 4, TB, 0, stream>>>(ent);

    const unsigned short* hin = hb0;
    for (int j = 1; j < KPOW; ++j) {
        float* hout = out + (size_t)j * N_FEAT;
        unsigned short* houtb = (j == 1) ? hb1 : hb2;
        int write_bf = (j < KPOW - 1) ? 1 : 0;
        k_spmm<<<N_NODES / 4, TB, 0, stream>>>(len, ent, hin, hout, houtb, write_bf);
        hin = houtb;
    }
}